// Round 1
// baseline (295.078 us; speedup 1.0000x reference)
//
#include <hip/hip_runtime.h>
#include <hip/hip_bf16.h>
#include <math.h>

#define P_N   2048
#define B_N   10000
#define NB    15
#define MROWS (P_N * NB)   // 30720

typedef __bf16 bf16x8 __attribute__((ext_vector_type(8)));
typedef float  f32x4  __attribute__((ext_vector_type(4)));

__device__ __forceinline__ float bf2f(unsigned short u) {
    union { unsigned int i; float f; } v; v.i = ((unsigned int)u) << 16; return v.f;
}
__device__ __forceinline__ unsigned short f2bf(float f) {
    union { float f; unsigned int i; } v; v.f = f;
    unsigned int i = v.i;
    i += 0x7FFFu + ((i >> 16) & 1u);
    return (unsigned short)(i >> 16);
}

// ---------------- K0: zero stats, convert W1/W2 -> bf16 transposed [N][K] ----
__global__ void k_prep(const float* __restrict__ W1, const float* __restrict__ W2,
                       unsigned short* __restrict__ w1t, unsigned short* __restrict__ w2t,
                       float* __restrict__ stats) {
    int idx = blockIdx.x * 256 + threadIdx.x;
    if (idx < 3072) stats[idx] = 0.0f;
    if (idx < 128 * 512) {                 // W1: [128][512] -> w1t [512][128]
        int k = idx >> 9, n = idx & 511;
        w1t[n * 128 + k] = f2bf(W1[idx]);
    }
    if (idx < 512 * 1024) {                // W2: [512][1024] -> w2t [1024][512]
        int k = idx >> 10, n = idx & 1023;
        w2t[n * 512 + k] = f2bf(W2[idx]);
    }
}

// ---------------- K1: polar grid argmin + spatial embedding + h assembly -----
__global__ __launch_bounds__(256) void k_grid(
        const float* __restrict__ end_pos, const float* __restrict__ rel_pos,
        const float* __restrict__ bpts, const float* __restrict__ Wsp,
        const float* __restrict__ bsp, const float* __restrict__ h,
        unsigned short* __restrict__ X) {
    __shared__ float  s_r2[NB * 256];
    __shared__ int    s_ix[NB * 256];
    __shared__ float  f_r2[NB];
    __shared__ int    f_ix[NB];
    __shared__ float2 s_rel[NB];

    int p = blockIdx.x, tid = threadIdx.x;
    float ex = end_pos[2 * p], ey = end_pos[2 * p + 1];
    float rx = rel_pos[2 * p], ry = rel_pos[2 * p + 1];
    float rr = rx * rx + ry * ry;
    float c, s;
    if (rr > 0.0f) { float inv = 1.0f / sqrtf(rr); c = rx * inv; s = ry * inv; }
    else           { c = 1.0f; s = 0.0f; }

    // tan of interior bin boundaries: -pi/2 + k*pi/15, k=1..14
    const float T[14] = { -4.704630109f, -2.246036774f, -1.376381920f, -0.900404044f,
                          -0.577350269f, -0.324919696f, -0.105104235f,  0.105104235f,
                           0.324919696f,  0.577350269f,  0.900404044f,  1.376381920f,
                           2.246036774f,  4.704630109f };

    float br2[NB]; int bix[NB];
#pragma unroll
    for (int k = 0; k < NB; ++k) { br2[k] = 3.0e38f; bix[k] = 0x7fffffff; }

    const float2* bp2 = (const float2*)bpts;
    for (int b = tid; b < B_N; b += 256) {
        float2 pt = bp2[b];
        float dx = pt.x - ex, dy = pt.y - ey;
        float xb = dx * c + dy * s;          // rotate into ped frame
        float yb = dy * c - dx * s;
        bool valid = xb > 0.0f;              // th in (-pi/2, pi/2)
        float r2 = xb * xb + yb * yb;
        int bin = 0;
#pragma unroll
        for (int k = 0; k < 14; ++k) bin += (yb > T[k] * xb) ? 1 : 0;
#pragma unroll
        for (int k = 0; k < NB; ++k) {       // static unroll: stays in registers
            bool better = valid && (bin == k) && (r2 < br2[k]);
            if (better) { br2[k] = r2; bix[k] = b; }
        }
    }
#pragma unroll
    for (int k = 0; k < NB; ++k) { s_r2[k * 256 + tid] = br2[k]; s_ix[k * 256 + tid] = bix[k]; }
    __syncthreads();

    int wv = tid >> 6, ln = tid & 63;
    for (int bin = wv; bin < NB; bin += 4) {
        float r = s_r2[bin * 256 + ln]; int ix = s_ix[bin * 256 + ln];
#pragma unroll
        for (int o = 64; o < 256; o += 64) {
            float ro = s_r2[bin * 256 + ln + o]; int io = s_ix[bin * 256 + ln + o];
            if (ro < r || (ro == r && io < ix)) { r = ro; ix = io; }
        }
#pragma unroll
        for (int d = 32; d >= 1; d >>= 1) {
            float ro = __shfl_xor(r, d, 64); int io = __shfl_xor(ix, d, 64);
            if (ro < r || (ro == r && io < ix)) { r = ro; ix = io; }
        }
        if (ln == 0) { f_r2[bin] = r; f_ix[bin] = ix; }
    }
    __syncthreads();

    if (tid < NB) {
        float rmin = sqrtf(f_r2[tid]);
        float relx, rely;
        if (rmin <= 2.0f) {                  // boundary point wins (incl. tie)
            int b = f_ix[tid];
            relx = bpts[2 * b] - ex; rely = bpts[2 * b + 1] - ey;
        } else {                             // fallback: r=2 at bin center
            float th = ((float)tid + 0.5f) * (float)(M_PI / 15.0) - (float)(M_PI / 2.0);
            float xc = 2.0f * cosf(th), yc = 2.0f * sinf(th);
            relx = xc * c - yc * s;
            rely = xc * s + yc * c;
        }
        s_rel[tid] = make_float2(relx, rely);
    }
    __syncthreads();

    for (int q = tid; q < NB * 64; q += 256) {
        int cell = q >> 6, e = q & 63;
        float2 rel = s_rel[cell];
        float emb = rel.x * Wsp[e] + rel.y * Wsp[64 + e] + bsp[e];
        size_t row = (size_t)p * NB + cell;
        X[row * 128 + e]      = f2bf(emb);
        X[row * 128 + 64 + e] = f2bf(h[(size_t)p * 64 + e]);
    }
}

// ---------------- GEMM: C[M][N] = A[M][K] @ Bt[N][K]^T + bias, bf16 in/out ---
__global__ __launch_bounds__(256) void k_gemm(
        const unsigned short* __restrict__ A, const unsigned short* __restrict__ Bt,
        const float* __restrict__ bias, unsigned short* __restrict__ C,
        int M, int N, int K) {
    __shared__ __align__(16) unsigned short lds[2][128 * 40];   // +8 pad per row
    int tid = threadIdx.x;
    int tiles_m = M >> 7;
    int bm = blockIdx.x % tiles_m, bn = blockIdx.x / tiles_m;
    int row0 = bm << 7, col0 = bn << 7;
    int lane = tid & 63, wave = tid >> 6;
    int wr = wave >> 1, wc = wave & 1;
    int frow = lane & 15, fkb = (lane >> 4) << 3;

    f32x4 zero = {0.f, 0.f, 0.f, 0.f};
    f32x4 acc[4][4];
#pragma unroll
    for (int i = 0; i < 4; ++i)
#pragma unroll
        for (int j = 0; j < 4; ++j) acc[i][j] = zero;

    int srow = tid >> 2, sseg = tid & 3;
    for (int k0 = 0; k0 < K; k0 += 32) {
        __syncthreads();
#pragma unroll
        for (int half = 0; half < 2; ++half) {
            int row = srow + half * 64;
            uint4 va = *(const uint4*)(A  + (size_t)(row0 + row) * K + k0 + sseg * 8);
            uint4 vb = *(const uint4*)(Bt + (size_t)(col0 + row) * K + k0 + sseg * 8);
            *(uint4*)&lds[0][row * 40 + sseg * 8] = va;
            *(uint4*)&lds[1][row * 40 + sseg * 8] = vb;
        }
        __syncthreads();
        bf16x8 af[4], bfv[4];
#pragma unroll
        for (int i = 0; i < 4; ++i) {
            af[i]  = *(const bf16x8*)&lds[0][(wr * 64 + i * 16 + frow) * 40 + fkb];
            bfv[i] = *(const bf16x8*)&lds[1][(wc * 64 + i * 16 + frow) * 40 + fkb];
        }
#pragma unroll
        for (int i = 0; i < 4; ++i)
#pragma unroll
            for (int j = 0; j < 4; ++j)
                acc[i][j] = __builtin_amdgcn_mfma_f32_16x16x32_bf16(af[i], bfv[j], acc[i][j], 0, 0, 0);
    }

#pragma unroll
    for (int j = 0; j < 4; ++j) {
        int col = col0 + wc * 64 + j * 16 + frow;
        float bv = bias[col];
#pragma unroll
        for (int i = 0; i < 4; ++i) {
#pragma unroll
            for (int r = 0; r < 4; ++r) {
                int row = row0 + wr * 64 + i * 16 + ((lane >> 4) << 2) + r;
                C[(size_t)row * N + col] = f2bf(acc[i][j][r] + bv);
            }
        }
    }
}

// ---------------- column stats: sum, sumsq over rows -------------------------
__global__ void k_colstats(const unsigned short* __restrict__ Xm, float* __restrict__ sum,
                           float* __restrict__ sumsq, int Ncols) {
    int c = blockIdx.x * 256 + threadIdx.x;
    int r0 = blockIdx.y * 128;
    float s = 0.f, q = 0.f;
    for (int r = r0; r < r0 + 128; ++r) {
        float v = bf2f(Xm[(size_t)r * Ncols + c]);
        s += v; q = fmaf(v, v, q);
    }
    atomicAdd(&sum[c], s);
    atomicAdd(&sumsq[c], q);
}

// ---------------- BN + ReLU, in place, 8 elems/thread ------------------------
__global__ void k_bnrelu(unsigned short* __restrict__ Y, const float* __restrict__ sum,
                         const float* __restrict__ sumsq, const float* __restrict__ g,
                         const float* __restrict__ be, int Ncols, unsigned int total8) {
    unsigned int idx = blockIdx.x * 256 + threadIdx.x;
    if (idx >= total8) return;
    size_t e0 = (size_t)idx * 8;
    int c0 = (int)(e0 % (size_t)Ncols);
    uint4 v = *(const uint4*)(Y + e0);
    unsigned short* u = (unsigned short*)&v;
    const float invN = 1.0f / (float)MROWS;
#pragma unroll
    for (int j = 0; j < 8; ++j) {
        int cc = c0 + j;
        float mean = sum[cc] * invN;
        float var  = sumsq[cc] * invN - mean * mean;
        float sc = g[cc] * rsqrtf(var + 1e-5f);
        float sh = be[cc] - mean * sc;
        float x = bf2f(u[j]) * sc + sh;
        u[j] = f2bf(fmaxf(x, 0.0f));
    }
    *(uint4*)(Y + e0) = v;
}

// ---------------- BN2 + ReLU + max over 15 cells -> out (f32) ----------------
__global__ void k_bnmax(const unsigned short* __restrict__ Y2, const float* __restrict__ sum,
                        const float* __restrict__ sumsq, const float* __restrict__ g,
                        const float* __restrict__ be, float* __restrict__ out) {
    int idx = blockIdx.x * 256 + threadIdx.x;      // 2048*128 threads
    int p = idx >> 7, cb = idx & 127;
    int c0 = cb << 3;
    const float invN = 1.0f / (float)MROWS;
    float sc[8], sh[8];
#pragma unroll
    for (int j = 0; j < 8; ++j) {
        int cc = c0 + j;
        float mean = sum[cc] * invN;
        float var  = sumsq[cc] * invN - mean * mean;
        sc[j] = g[cc] * rsqrtf(var + 1e-5f);
        sh[j] = be[cc] - mean * sc[j];
    }
    float mx[8];
#pragma unroll
    for (int j = 0; j < 8; ++j) mx[j] = -3.0e38f;
#pragma unroll
    for (int cell = 0; cell < NB; ++cell) {
        uint4 v = *(const uint4*)(Y2 + ((size_t)(p * NB + cell)) * 1024 + c0);
        const unsigned short* u = (const unsigned short*)&v;
#pragma unroll
        for (int j = 0; j < 8; ++j) {
            float x = bf2f(u[j]) * sc[j] + sh[j];
            mx[j] = fmaxf(mx[j], x);
        }
    }
    float4 o0, o1;
    o0.x = fmaxf(mx[0], 0.f); o0.y = fmaxf(mx[1], 0.f);
    o0.z = fmaxf(mx[2], 0.f); o0.w = fmaxf(mx[3], 0.f);
    o1.x = fmaxf(mx[4], 0.f); o1.y = fmaxf(mx[5], 0.f);
    o1.z = fmaxf(mx[6], 0.f); o1.w = fmaxf(mx[7], 0.f);
    *(float4*)(out + (size_t)p * 1024 + c0)     = o0;
    *(float4*)(out + (size_t)p * 1024 + c0 + 4) = o1;
}

extern "C" void kernel_launch(void* const* d_in, const int* in_sizes, int n_in,
                              void* d_out, int out_size, void* d_ws, size_t ws_size,
                              hipStream_t stream) {
    const float* h       = (const float*)d_in[0];
    const float* end_pos = (const float*)d_in[1];
    const float* rel_pos = (const float*)d_in[2];
    const float* bpts    = (const float*)d_in[3];
    const float* Wsp     = (const float*)d_in[4];
    const float* bsp     = (const float*)d_in[5];
    const float* W1      = (const float*)d_in[6];
    const float* b1      = (const float*)d_in[7];
    const float* g1      = (const float*)d_in[8];
    const float* be1     = (const float*)d_in[9];
    const float* W2      = (const float*)d_in[10];
    const float* b2      = (const float*)d_in[11];
    const float* g2      = (const float*)d_in[12];
    const float* be2     = (const float*)d_in[13];
    float* out = (float*)d_out;

    char* ws = (char*)d_ws;
    float* stats = (float*)ws;                       // 3072 f32: s1,q1,s2,q2
    float* s1 = stats;
    float* q1 = s1 + 512;
    float* s2 = q1 + 512;
    float* q2 = s2 + 1024;
    unsigned short* w1t = (unsigned short*)(ws + 16384);        // [512][128]
    unsigned short* w2t = w1t + (size_t)512 * 128;              // [1024][512]
    unsigned short* X   = w2t + (size_t)1024 * 512;             // [30720][128]
    unsigned short* Y1  = X   + (size_t)MROWS * 128;            // [30720][512]
    unsigned short* Y2  = Y1  + (size_t)MROWS * 512;            // [30720][1024]

    k_prep<<<2048, 256, 0, stream>>>(W1, W2, w1t, w2t, stats);
    k_grid<<<P_N, 256, 0, stream>>>(end_pos, rel_pos, bpts, Wsp, bsp, h, X);
    k_gemm<<<(MROWS / 128) * (512 / 128), 256, 0, stream>>>(X, w1t, b1, Y1, MROWS, 512, 128);
    k_colstats<<<dim3(512 / 256, MROWS / 128), 256, 0, stream>>>(Y1, s1, q1, 512);
    k_bnrelu<<<(MROWS * 512 / 8) / 256, 256, 0, stream>>>(Y1, s1, q1, g1, be1, 512,
                                                          (unsigned int)(MROWS * 512 / 8));
    k_gemm<<<(MROWS / 128) * (1024 / 128), 256, 0, stream>>>(Y1, w2t, b2, Y2, MROWS, 1024, 512);
    k_colstats<<<dim3(1024 / 256, MROWS / 128), 256, 0, stream>>>(Y2, s2, q2, 1024);
    k_bnmax<<<(P_N * 128) / 256, 256, 0, stream>>>(Y2, s2, q2, g2, be2, out);
}

// Round 2
// 221.599 us; speedup vs baseline: 1.3316x; 1.3316x over previous
//
#include <hip/hip_runtime.h>
#include <hip/hip_bf16.h>
#include <math.h>

#define P_N   2048
#define B_N   10000
#define NB    15
#define MROWS (P_N * NB)   // 30720

typedef __bf16 bf16x8 __attribute__((ext_vector_type(8)));
typedef float  f32x4  __attribute__((ext_vector_type(4)));

__device__ __forceinline__ float bf2f(unsigned short u) {
    union { unsigned int i; float f; } v; v.i = ((unsigned int)u) << 16; return v.f;
}
__device__ __forceinline__ unsigned short f2bf(float f) {
    union { float f; unsigned int i; } v; v.f = f;
    unsigned int i = v.i;
    i += 0x7FFFu + ((i >> 16) & 1u);
    return (unsigned short)(i >> 16);
}

// ---------------- K0: zero stats, convert W1/W2 -> bf16 transposed [N][K] ----
__global__ void k_prep(const float* __restrict__ W1, const float* __restrict__ W2,
                       unsigned short* __restrict__ w1t, unsigned short* __restrict__ w2t,
                       float* __restrict__ stats) {
    int idx = blockIdx.x * 256 + threadIdx.x;
    if (idx < 3072) stats[idx] = 0.0f;
    if (idx < 128 * 512) {                 // W1: [128][512] -> w1t [512][128]
        int k = idx >> 9, n = idx & 511;
        w1t[n * 128 + k] = f2bf(W1[idx]);
    }
    if (idx < 512 * 1024) {                // W2: [512][1024] -> w2t [1024][512]
        int k = idx >> 10, n = idx & 1023;
        w2t[n * 512 + k] = f2bf(W2[idx]);
    }
}

// ---------------- K1: polar grid argmin + spatial embedding + h assembly -----
__global__ __launch_bounds__(256) void k_grid(
        const float* __restrict__ end_pos, const float* __restrict__ rel_pos,
        const float* __restrict__ bpts, const float* __restrict__ Wsp,
        const float* __restrict__ bsp, const float* __restrict__ h,
        unsigned short* __restrict__ X) {
    __shared__ float  s_r2[NB * 256];
    __shared__ int    s_ix[NB * 256];
    __shared__ float  f_r2[NB];
    __shared__ int    f_ix[NB];
    __shared__ float2 s_rel[NB];

    int p = blockIdx.x, tid = threadIdx.x;
    float ex = end_pos[2 * p], ey = end_pos[2 * p + 1];
    float rx = rel_pos[2 * p], ry = rel_pos[2 * p + 1];
    float rr = rx * rx + ry * ry;
    float c, s;
    if (rr > 0.0f) { float inv = 1.0f / sqrtf(rr); c = rx * inv; s = ry * inv; }
    else           { c = 1.0f; s = 0.0f; }

    // tan of interior bin boundaries: -pi/2 + k*pi/15, k=1..14
    const float T[14] = { -4.704630109f, -2.246036774f, -1.376381920f, -0.900404044f,
                          -0.577350269f, -0.324919696f, -0.105104235f,  0.105104235f,
                           0.324919696f,  0.577350269f,  0.900404044f,  1.376381920f,
                           2.246036774f,  4.704630109f };

    float br2[NB]; int bix[NB];
#pragma unroll
    for (int k = 0; k < NB; ++k) { br2[k] = 3.0e38f; bix[k] = 0x7fffffff; }

    const float2* bp2 = (const float2*)bpts;
    for (int b = tid; b < B_N; b += 256) {
        float2 pt = bp2[b];
        float dx = pt.x - ex, dy = pt.y - ey;
        float xb = dx * c + dy * s;          // rotate into ped frame
        float yb = dy * c - dx * s;
        bool valid = xb > 0.0f;              // th in (-pi/2, pi/2)
        float r2 = xb * xb + yb * yb;
        int bin = 0;
#pragma unroll
        for (int k = 0; k < 14; ++k) bin += (yb > T[k] * xb) ? 1 : 0;
#pragma unroll
        for (int k = 0; k < NB; ++k) {       // static unroll: stays in registers
            bool better = valid && (bin == k) && (r2 < br2[k]);
            if (better) { br2[k] = r2; bix[k] = b; }
        }
    }
#pragma unroll
    for (int k = 0; k < NB; ++k) { s_r2[k * 256 + tid] = br2[k]; s_ix[k * 256 + tid] = bix[k]; }
    __syncthreads();

    int wv = tid >> 6, ln = tid & 63;
    for (int bin = wv; bin < NB; bin += 4) {
        float r = s_r2[bin * 256 + ln]; int ix = s_ix[bin * 256 + ln];
#pragma unroll
        for (int o = 64; o < 256; o += 64) {
            float ro = s_r2[bin * 256 + ln + o]; int io = s_ix[bin * 256 + ln + o];
            if (ro < r || (ro == r && io < ix)) { r = ro; ix = io; }
        }
#pragma unroll
        for (int d = 32; d >= 1; d >>= 1) {
            float ro = __shfl_xor(r, d, 64); int io = __shfl_xor(ix, d, 64);
            if (ro < r || (ro == r && io < ix)) { r = ro; ix = io; }
        }
        if (ln == 0) { f_r2[bin] = r; f_ix[bin] = ix; }
    }
    __syncthreads();

    if (tid < NB) {
        float rmin = sqrtf(f_r2[tid]);
        float relx, rely;
        if (rmin <= 2.0f) {                  // boundary point wins (incl. tie)
            int b = f_ix[tid];
            relx = bpts[2 * b] - ex; rely = bpts[2 * b + 1] - ey;
        } else {                             // fallback: r=2 at bin center
            float th = ((float)tid + 0.5f) * (float)(M_PI / 15.0) - (float)(M_PI / 2.0);
            float xc = 2.0f * cosf(th), yc = 2.0f * sinf(th);
            relx = xc * c - yc * s;
            rely = xc * s + yc * c;
        }
        s_rel[tid] = make_float2(relx, rely);
    }
    __syncthreads();

    for (int q = tid; q < NB * 64; q += 256) {
        int cell = q >> 6, e = q & 63;
        float2 rel = s_rel[cell];
        float emb = rel.x * Wsp[e] + rel.y * Wsp[64 + e] + bsp[e];
        size_t row = (size_t)p * NB + cell;
        X[row * 128 + e]      = f2bf(emb);
        X[row * 128 + 64 + e] = f2bf(h[(size_t)p * 64 + e]);
    }
}

// ---------------- GEMM: C[M][N] = A[M][K] @ Bt[N][K]^T + bias, bf16 in/out ---
__global__ __launch_bounds__(256) void k_gemm(
        const unsigned short* __restrict__ A, const unsigned short* __restrict__ Bt,
        const float* __restrict__ bias, unsigned short* __restrict__ C,
        int M, int N, int K) {
    __shared__ __align__(16) unsigned short lds[2][128 * 40];   // +8 pad per row
    int tid = threadIdx.x;
    int tiles_m = M >> 7;
    int bm = blockIdx.x % tiles_m, bn = blockIdx.x / tiles_m;
    int row0 = bm << 7, col0 = bn << 7;
    int lane = tid & 63, wave = tid >> 6;
    int wr = wave >> 1, wc = wave & 1;
    int frow = lane & 15, fkb = (lane >> 4) << 3;

    f32x4 zero = {0.f, 0.f, 0.f, 0.f};
    f32x4 acc[4][4];
#pragma unroll
    for (int i = 0; i < 4; ++i)
#pragma unroll
        for (int j = 0; j < 4; ++j) acc[i][j] = zero;

    int srow = tid >> 2, sseg = tid & 3;
    for (int k0 = 0; k0 < K; k0 += 32) {
        __syncthreads();
#pragma unroll
        for (int half = 0; half < 2; ++half) {
            int row = srow + half * 64;
            uint4 va = *(const uint4*)(A  + (size_t)(row0 + row) * K + k0 + sseg * 8);
            uint4 vb = *(const uint4*)(Bt + (size_t)(col0 + row) * K + k0 + sseg * 8);
            *(uint4*)&lds[0][row * 40 + sseg * 8] = va;
            *(uint4*)&lds[1][row * 40 + sseg * 8] = vb;
        }
        __syncthreads();
        bf16x8 af[4], bfv[4];
#pragma unroll
        for (int i = 0; i < 4; ++i) {
            af[i]  = *(const bf16x8*)&lds[0][(wr * 64 + i * 16 + frow) * 40 + fkb];
            bfv[i] = *(const bf16x8*)&lds[1][(wc * 64 + i * 16 + frow) * 40 + fkb];
        }
#pragma unroll
        for (int i = 0; i < 4; ++i)
#pragma unroll
            for (int j = 0; j < 4; ++j)
                acc[i][j] = __builtin_amdgcn_mfma_f32_16x16x32_bf16(af[i], bfv[j], acc[i][j], 0, 0, 0);
    }

#pragma unroll
    for (int j = 0; j < 4; ++j) {
        int col = col0 + wc * 64 + j * 16 + frow;
        float bv = bias[col];
#pragma unroll
        for (int i = 0; i < 4; ++i) {
#pragma unroll
            for (int r = 0; r < 4; ++r) {
                int row = row0 + wr * 64 + i * 16 + ((lane >> 4) << 2) + r;
                C[(size_t)row * N + col] = f2bf(acc[i][j][r] + bv);
            }
        }
    }
}

// ---------------- column stats: sum, sumsq over rows (column-resident) -------
__global__ __launch_bounds__(256) void k_colstats(const unsigned short* __restrict__ Xm,
        float* __restrict__ sum, float* __restrict__ sumsq, int Ncols) {
    __shared__ float s_s[1024], s_q[1024];
    int tid = threadIdx.x;
    int SEGS = Ncols >> 3;                      // uint4 segments per row
    int seg  = tid & (SEGS - 1);
    int roff = tid / SEGS;
    int rstep = 256 / SEGS;
    int r0 = blockIdx.x * 128;
    for (int i = tid; i < Ncols; i += 256) { s_s[i] = 0.f; s_q[i] = 0.f; }
    __syncthreads();
    float s[8] = {0, 0, 0, 0, 0, 0, 0, 0}, q[8] = {0, 0, 0, 0, 0, 0, 0, 0};
    for (int r = r0 + roff; r < r0 + 128; r += rstep) {
        uint4 v = *(const uint4*)(Xm + (size_t)r * Ncols + seg * 8);
        const unsigned short* u = (const unsigned short*)&v;
#pragma unroll
        for (int j = 0; j < 8; ++j) { float x = bf2f(u[j]); s[j] += x; q[j] = fmaf(x, x, q[j]); }
    }
#pragma unroll
    for (int j = 0; j < 8; ++j) {
        atomicAdd(&s_s[seg * 8 + j], s[j]);
        atomicAdd(&s_q[seg * 8 + j], q[j]);
    }
    __syncthreads();
    for (int c = tid; c < Ncols; c += 256) {
        atomicAdd(&sum[c], s_s[c]);
        atomicAdd(&sumsq[c], s_q[c]);
    }
}

// ---------------- finalize: per-column affine coefficients -------------------
__global__ void k_finalize(const float* __restrict__ s, const float* __restrict__ q,
                           const float* __restrict__ g, const float* __restrict__ be,
                           float* __restrict__ sc, float* __restrict__ sh, int Ncols) {
    int i = blockIdx.x * 256 + threadIdx.x;
    if (i >= Ncols) return;
    const float invN = 1.0f / (float)MROWS;
    float m = s[i] * invN;
    float v = q[i] * invN - m * m;
    float k = g[i] * rsqrtf(v + 1e-5f);
    sc[i] = k;
    sh[i] = be[i] - m * k;
}

// ---------------- BN + ReLU, in place, column-resident streaming -------------
__global__ __launch_bounds__(256) void k_bnrelu(unsigned short* __restrict__ Y,
        const float* __restrict__ sc, const float* __restrict__ sh, int Ncols) {
    int tid = threadIdx.x;
    int SEGS = Ncols >> 3;
    int seg  = tid & (SEGS - 1);
    int roff = tid / SEGS;
    int rstep = 256 / SEGS;
    int r0 = blockIdx.x * 128;
    float4 sc0 = *(const float4*)(sc + seg * 8);
    float4 sc1 = *(const float4*)(sc + seg * 8 + 4);
    float4 sh0 = *(const float4*)(sh + seg * 8);
    float4 sh1 = *(const float4*)(sh + seg * 8 + 4);
    float scv[8] = {sc0.x, sc0.y, sc0.z, sc0.w, sc1.x, sc1.y, sc1.z, sc1.w};
    float shv[8] = {sh0.x, sh0.y, sh0.z, sh0.w, sh1.x, sh1.y, sh1.z, sh1.w};
    for (int r = r0 + roff; r < r0 + 128; r += rstep) {
        unsigned short* p = Y + (size_t)r * Ncols + seg * 8;
        uint4 v = *(const uint4*)p;
        unsigned short* u = (unsigned short*)&v;
#pragma unroll
        for (int j = 0; j < 8; ++j) {
            float x = fmaf(bf2f(u[j]), scv[j], shv[j]);
            u[j] = f2bf(fmaxf(x, 0.0f));
        }
        *(uint4*)p = v;
    }
}

// ---------------- BN2 + ReLU + max over 15 cells -> out (f32) ----------------
__global__ void k_bnmax(const unsigned short* __restrict__ Y2, const float* __restrict__ sc,
                        const float* __restrict__ sh, float* __restrict__ out) {
    int idx = blockIdx.x * 256 + threadIdx.x;      // 2048*128 threads
    int p = idx >> 7, cb = idx & 127;
    int c0 = cb << 3;
    float4 a0 = *(const float4*)(sc + c0);
    float4 a1 = *(const float4*)(sc + c0 + 4);
    float4 h0 = *(const float4*)(sh + c0);
    float4 h1 = *(const float4*)(sh + c0 + 4);
    float scv[8] = {a0.x, a0.y, a0.z, a0.w, a1.x, a1.y, a1.z, a1.w};
    float shv[8] = {h0.x, h0.y, h0.z, h0.w, h1.x, h1.y, h1.z, h1.w};
    float mx[8];
#pragma unroll
    for (int j = 0; j < 8; ++j) mx[j] = -3.0e38f;
#pragma unroll
    for (int cell = 0; cell < NB; ++cell) {
        uint4 v = *(const uint4*)(Y2 + ((size_t)(p * NB + cell)) * 1024 + c0);
        const unsigned short* u = (const unsigned short*)&v;
#pragma unroll
        for (int j = 0; j < 8; ++j) {
            float x = fmaf(bf2f(u[j]), scv[j], shv[j]);
            mx[j] = fmaxf(mx[j], x);
        }
    }
    float4 o0, o1;
    o0.x = fmaxf(mx[0], 0.f); o0.y = fmaxf(mx[1], 0.f);
    o0.z = fmaxf(mx[2], 0.f); o0.w = fmaxf(mx[3], 0.f);
    o1.x = fmaxf(mx[4], 0.f); o1.y = fmaxf(mx[5], 0.f);
    o1.z = fmaxf(mx[6], 0.f); o1.w = fmaxf(mx[7], 0.f);
    *(float4*)(out + (size_t)p * 1024 + c0)     = o0;
    *(float4*)(out + (size_t)p * 1024 + c0 + 4) = o1;
}

extern "C" void kernel_launch(void* const* d_in, const int* in_sizes, int n_in,
                              void* d_out, int out_size, void* d_ws, size_t ws_size,
                              hipStream_t stream) {
    const float* h       = (const float*)d_in[0];
    const float* end_pos = (const float*)d_in[1];
    const float* rel_pos = (const float*)d_in[2];
    const float* bpts    = (const float*)d_in[3];
    const float* Wsp     = (const float*)d_in[4];
    const float* bsp     = (const float*)d_in[5];
    const float* W1      = (const float*)d_in[6];
    const float* b1      = (const float*)d_in[7];
    const float* g1      = (const float*)d_in[8];
    const float* be1     = (const float*)d_in[9];
    const float* W2      = (const float*)d_in[10];
    const float* b2      = (const float*)d_in[11];
    const float* g2      = (const float*)d_in[12];
    const float* be2     = (const float*)d_in[13];
    float* out = (float*)d_out;

    char* ws = (char*)d_ws;
    float* s1  = (float*)ws;                 // zeroed by k_prep (first 3072 f32)
    float* q1  = s1 + 512;
    float* s2  = q1 + 512;
    float* q2  = s2 + 1024;
    float* sc1 = q2 + 1024;                  // written by k_finalize
    float* sh1 = sc1 + 512;
    float* sc2 = sh1 + 512;
    float* sh2 = sc2 + 1024;
    unsigned short* w1t = (unsigned short*)(ws + 32768);        // [512][128]
    unsigned short* w2t = w1t + (size_t)512 * 128;              // [1024][512]
    unsigned short* X   = w2t + (size_t)1024 * 512;             // [30720][128]
    unsigned short* Y1  = X   + (size_t)MROWS * 128;            // [30720][512]
    unsigned short* Y2  = Y1  + (size_t)MROWS * 512;            // [30720][1024]

    k_prep<<<2048, 256, 0, stream>>>(W1, W2, w1t, w2t, s1);
    k_grid<<<P_N, 256, 0, stream>>>(end_pos, rel_pos, bpts, Wsp, bsp, h, X);
    k_gemm<<<(MROWS / 128) * (512 / 128), 256, 0, stream>>>(X, w1t, b1, Y1, MROWS, 512, 128);
    k_colstats<<<MROWS / 128, 256, 0, stream>>>(Y1, s1, q1, 512);
    k_finalize<<<2, 256, 0, stream>>>(s1, q1, g1, be1, sc1, sh1, 512);
    k_bnrelu<<<MROWS / 128, 256, 0, stream>>>(Y1, sc1, sh1, 512);
    k_gemm<<<(MROWS / 128) * (1024 / 128), 256, 0, stream>>>(Y1, w2t, b2, Y2, MROWS, 1024, 512);
    k_colstats<<<MROWS / 128, 256, 0, stream>>>(Y2, s2, q2, 1024);
    k_finalize<<<4, 256, 0, stream>>>(s2, q2, g2, be2, sc2, sh2, 1024);
    k_bnmax<<<(P_N * 128) / 256, 256, 0, stream>>>(Y2, sc2, sh2, out);
}

// Round 3
// 186.199 us; speedup vs baseline: 1.5847x; 1.1901x over previous
//
#include <hip/hip_runtime.h>
#include <hip/hip_bf16.h>
#include <math.h>

#define P_N   2048
#define B_N   10000
#define NB    15
#define MROWS (P_N * NB)   // 30720
#define SPLIT 5
#define BPB   (B_N / SPLIT)  // 2000 boundary points per scan block

typedef __bf16 bf16x8 __attribute__((ext_vector_type(8)));
typedef float  f32x4  __attribute__((ext_vector_type(4)));

__device__ __forceinline__ float bf2f(unsigned short u) {
    union { unsigned int i; float f; } v; v.i = ((unsigned int)u) << 16; return v.f;
}
__device__ __forceinline__ unsigned short f2bf(float f) {
    union { float f; unsigned int i; } v; v.f = f;
    unsigned int i = v.i;
    i += 0x7FFFu + ((i >> 16) & 1u);
    return (unsigned short)(i >> 16);
}

// ---- K0: zero stats, init keys, convert W1/W2 -> bf16 transposed [N][K] ----
__global__ void k_prep(const float* __restrict__ W1, const float* __restrict__ W2,
                       unsigned short* __restrict__ w1t, unsigned short* __restrict__ w2t,
                       float* __restrict__ stats, unsigned long long* __restrict__ keys) {
    int idx = blockIdx.x * 256 + threadIdx.x;
    if (idx < 3072) stats[idx] = 0.0f;
    if (idx < MROWS) keys[idx] = ~0ull;
    if (idx < 128 * 512) {                 // W1: [128][512] -> w1t [512][128]
        int k = idx >> 9, n = idx & 511;
        w1t[n * 128 + k] = f2bf(W1[idx]);
    }
    if (idx < 512 * 1024) {                // W2: [512][1024] -> w2t [1024][512]
        int k = idx >> 10, n = idx & 1023;
        w2t[n * 512 + k] = f2bf(W2[idx]);
    }
}

// ---- K1a: scan boundary points, per-bin min via packed u64 atomicMin --------
__global__ __launch_bounds__(256) void k_scan(
        const float* __restrict__ end_pos, const float* __restrict__ rel_pos,
        const float* __restrict__ bpts, unsigned long long* __restrict__ keys) {
    __shared__ unsigned long long s_key[NB];
    int tid = threadIdx.x;
    int p = blockIdx.x / SPLIT, part = blockIdx.x % SPLIT;
    if (tid < NB) s_key[tid] = ~0ull;
    __syncthreads();

    float ex = end_pos[2 * p], ey = end_pos[2 * p + 1];
    float rx = rel_pos[2 * p], ry = rel_pos[2 * p + 1];
    float rr = rx * rx + ry * ry;
    float c, s;
    if (rr > 0.0f) { float inv = 1.0f / sqrtf(rr); c = rx * inv; s = ry * inv; }
    else           { c = 1.0f; s = 0.0f; }

    // tan of bin boundaries -pi/2 + m*pi/15, m = 1..14  (T[m-1])
    const float T0 = -4.704630109f, T1 = -2.246036774f, T2 = -1.376381920f,
                T3 = -0.900404044f, T4 = -0.577350269f, T5 = -0.324919696f,
                T6 = -0.105104235f, T7 =  0.105104235f, T8 =  0.324919696f,
                T9 =  0.577350269f, T10 = 0.900404044f, T11 = 1.376381920f,
                T12 = 2.246036774f, T13 = 4.704630109f;

    const float2* bp2 = (const float2*)bpts;
    int bstart = part * BPB;
    for (int b = bstart + tid; b < bstart + BPB; b += 256) {
        float2 pt = bp2[b];
        float dx = pt.x - ex, dy = pt.y - ey;
        float xb = dx * c + dy * s;          // rotate into ped frame
        float yb = dy * c - dx * s;
        float r2 = xb * xb + yb * yb;
        // binary search for bin = #{m: yb > T[m-1]*xb}  (valid only when xb>0)
        bool v3 = yb > T7 * xb;
        float ta = v3 ? T11 : T3;
        bool v2 = yb > ta * xb;
        float tb = v3 ? (v2 ? T13 : T9) : (v2 ? T5 : T1);
        bool v1 = yb > tb * xb;
        float tc = v3 ? (v2 ? (v1 ? 3.0e38f : T12) : (v1 ? T10 : T8))
                      : (v2 ? (v1 ? T6 : T4)       : (v1 ? T2 : T0));
        bool v0 = yb > tc * xb;
        int bin = (v3 ? 8 : 0) + (v2 ? 4 : 0) + (v1 ? 2 : 0) + (v0 ? 1 : 0);
        if (xb > 0.0f) {
            unsigned long long key =
                ((unsigned long long)__float_as_uint(r2) << 32) | (unsigned int)b;
            atomicMin(&s_key[bin], key);
        }
    }
    __syncthreads();
    if (tid < NB) atomicMin(&keys[p * NB + tid], s_key[tid]);
}

// ---- K1b: choose point/fallback, build X = [emb(64) | h(64)] per (p,cell) ---
__global__ __launch_bounds__(256) void k_assemble(
        const unsigned long long* __restrict__ keys,
        const float* __restrict__ end_pos, const float* __restrict__ rel_pos,
        const float* __restrict__ bpts, const float* __restrict__ Wsp,
        const float* __restrict__ bsp, const float* __restrict__ h,
        unsigned short* __restrict__ X) {
    __shared__ float2 s_rel[NB];
    int p = blockIdx.x, tid = threadIdx.x;
    if (tid < NB) {
        float ex = end_pos[2 * p], ey = end_pos[2 * p + 1];
        unsigned long long key = keys[p * NB + tid];
        float r = sqrtf(__uint_as_float((unsigned int)(key >> 32)));
        float relx, rely;
        if (r <= 2.0f) {                     // real point wins (incl. exact tie)
            int b = (int)(key & 0xFFFFFFFFu);
            relx = bpts[2 * b] - ex; rely = bpts[2 * b + 1] - ey;
        } else {                             // fallback r=2 at bin center (NaN-safe)
            float rx = rel_pos[2 * p], ry = rel_pos[2 * p + 1];
            float rr = rx * rx + ry * ry;
            float c, s;
            if (rr > 0.0f) { float inv = 1.0f / sqrtf(rr); c = rx * inv; s = ry * inv; }
            else           { c = 1.0f; s = 0.0f; }
            float th = ((float)tid + 0.5f) * (float)(M_PI / 15.0) - (float)(M_PI / 2.0);
            float xc = 2.0f * cosf(th), yc = 2.0f * sinf(th);
            relx = xc * c - yc * s;
            rely = xc * s + yc * c;
        }
        s_rel[tid] = make_float2(relx, rely);
    }
    __syncthreads();
    if (tid < NB * 16) {
        int cell = tid >> 4, e0 = (tid & 15) * 8;
        float2 rel = s_rel[cell];
        unsigned short ubuf[8];
        if (e0 < 64) {
            float4 w0a = *(const float4*)(Wsp + e0),      w0b = *(const float4*)(Wsp + e0 + 4);
            float4 w1a = *(const float4*)(Wsp + 64 + e0), w1b = *(const float4*)(Wsp + 64 + e0 + 4);
            float4 bba = *(const float4*)(bsp + e0),      bbb = *(const float4*)(bsp + e0 + 4);
            float w0[8] = {w0a.x,w0a.y,w0a.z,w0a.w,w0b.x,w0b.y,w0b.z,w0b.w};
            float w1[8] = {w1a.x,w1a.y,w1a.z,w1a.w,w1b.x,w1b.y,w1b.z,w1b.w};
            float bb[8] = {bba.x,bba.y,bba.z,bba.w,bbb.x,bbb.y,bbb.z,bbb.w};
#pragma unroll
            for (int j = 0; j < 8; ++j)
                ubuf[j] = f2bf(rel.x * w0[j] + rel.y * w1[j] + bb[j]);
        } else {
            float4 ha = *(const float4*)(h + p * 64 + (e0 - 64));
            float4 hb = *(const float4*)(h + p * 64 + (e0 - 64) + 4);
            float hv[8] = {ha.x,ha.y,ha.z,ha.w,hb.x,hb.y,hb.z,hb.w};
#pragma unroll
            for (int j = 0; j < 8; ++j) ubuf[j] = f2bf(hv[j]);
        }
        *(uint4*)(X + ((size_t)p * NB + cell) * 128 + e0) = *(uint4*)ubuf;
    }
}

// ---- GEMM: C[M][N] = act(A)[M][K] @ Bt[N][K]^T + bias; optional fused BN-A
//      and fused column stats (sum, sumsq of y = acc+bias) ---------------------
template<bool BN_A, bool STATS>
__global__ __launch_bounds__(256) void k_gemm(
        const unsigned short* __restrict__ A, const unsigned short* __restrict__ Bt,
        const float* __restrict__ bias, unsigned short* __restrict__ C,
        int M, int N, int K,
        const float* __restrict__ scA, const float* __restrict__ shA,
        float* __restrict__ osum, float* __restrict__ osq) {
    __shared__ __align__(16) unsigned short lds[2][128 * 40];   // +8 pad per row
    int tid = threadIdx.x;
    int tiles_m = M >> 7;
    int bm = blockIdx.x % tiles_m, bn = blockIdx.x / tiles_m;
    int row0 = bm << 7, col0 = bn << 7;
    int lane = tid & 63, wave = tid >> 6;
    int wr = wave >> 1, wc = wave & 1;
    int frow = lane & 15, fkb = (lane >> 4) << 3;

    f32x4 zero = {0.f, 0.f, 0.f, 0.f};
    f32x4 acc[4][4];
#pragma unroll
    for (int i = 0; i < 4; ++i)
#pragma unroll
        for (int j = 0; j < 4; ++j) acc[i][j] = zero;

    int srow = tid >> 2, sseg = tid & 3;
    for (int k0 = 0; k0 < K; k0 += 32) {
        float sc8[8], sh8[8];
        if (BN_A) {
            float4 a0 = *(const float4*)(scA + k0 + sseg * 8);
            float4 a1 = *(const float4*)(scA + k0 + sseg * 8 + 4);
            float4 h0 = *(const float4*)(shA + k0 + sseg * 8);
            float4 h1 = *(const float4*)(shA + k0 + sseg * 8 + 4);
            sc8[0]=a0.x; sc8[1]=a0.y; sc8[2]=a0.z; sc8[3]=a0.w;
            sc8[4]=a1.x; sc8[5]=a1.y; sc8[6]=a1.z; sc8[7]=a1.w;
            sh8[0]=h0.x; sh8[1]=h0.y; sh8[2]=h0.z; sh8[3]=h0.w;
            sh8[4]=h1.x; sh8[5]=h1.y; sh8[6]=h1.z; sh8[7]=h1.w;
        }
        __syncthreads();
#pragma unroll
        for (int half = 0; half < 2; ++half) {
            int row = srow + half * 64;
            uint4 va = *(const uint4*)(A  + (size_t)(row0 + row) * K + k0 + sseg * 8);
            if (BN_A) {
                unsigned short* u = (unsigned short*)&va;
#pragma unroll
                for (int j = 0; j < 8; ++j) {
                    float x = fmaf(bf2f(u[j]), sc8[j], sh8[j]);
                    u[j] = f2bf(fmaxf(x, 0.0f));
                }
            }
            uint4 vb = *(const uint4*)(Bt + (size_t)(col0 + row) * K + k0 + sseg * 8);
            *(uint4*)&lds[0][row * 40 + sseg * 8] = va;
            *(uint4*)&lds[1][row * 40 + sseg * 8] = vb;
        }
        __syncthreads();
        bf16x8 af[4], bfv[4];
#pragma unroll
        for (int i = 0; i < 4; ++i) {
            af[i]  = *(const bf16x8*)&lds[0][(wr * 64 + i * 16 + frow) * 40 + fkb];
            bfv[i] = *(const bf16x8*)&lds[1][(wc * 64 + i * 16 + frow) * 40 + fkb];
        }
#pragma unroll
        for (int i = 0; i < 4; ++i)
#pragma unroll
            for (int j = 0; j < 4; ++j)
                acc[i][j] = __builtin_amdgcn_mfma_f32_16x16x32_bf16(af[i], bfv[j], acc[i][j], 0, 0, 0);
    }

#pragma unroll
    for (int j = 0; j < 4; ++j) {
        int col = col0 + wc * 64 + j * 16 + frow;
        float bv = bias[col];
        float csum = 0.f, csq = 0.f;
#pragma unroll
        for (int i = 0; i < 4; ++i) {
#pragma unroll
            for (int r = 0; r < 4; ++r) {
                int row = row0 + wr * 64 + i * 16 + ((lane >> 4) << 2) + r;
                float y = acc[i][j][r] + bv;
                C[(size_t)row * N + col] = f2bf(y);
                if (STATS) { csum += y; csq = fmaf(y, y, csq); }
            }
        }
        if (STATS) {
            csum += __shfl_xor(csum, 16);
            csum += __shfl_xor(csum, 32);
            csq  += __shfl_xor(csq, 16);
            csq  += __shfl_xor(csq, 32);
            if (lane < 16) {
                atomicAdd(&osum[col], csum);
                atomicAdd(&osq[col], csq);
            }
        }
    }
}

// ---- finalize: per-column affine coefficients (stage 1 only) ----------------
__global__ void k_finalize(const float* __restrict__ s, const float* __restrict__ q,
                           const float* __restrict__ g, const float* __restrict__ be,
                           float* __restrict__ sc, float* __restrict__ sh, int Ncols) {
    int i = blockIdx.x * 256 + threadIdx.x;
    if (i >= Ncols) return;
    const float invN = 1.0f / (float)MROWS;
    float m = s[i] * invN;
    float v = q[i] * invN - m * m;
    float k = g[i] * rsqrtf(v + 1e-5f);
    sc[i] = k;
    sh[i] = be[i] - m * k;
}

// ---- BN2 (inline coeffs) + ReLU + max over 15 cells -> out (f32) ------------
__global__ void k_bnmax(const unsigned short* __restrict__ Y2, const float* __restrict__ s2,
                        const float* __restrict__ q2, const float* __restrict__ g2,
                        const float* __restrict__ be2, float* __restrict__ out) {
    int idx = blockIdx.x * 256 + threadIdx.x;      // 2048*128 threads
    int p = idx >> 7, cb = idx & 127;
    int c0 = cb << 3;
    const float invN = 1.0f / (float)MROWS;
    float4 sa = *(const float4*)(s2 + c0),  sb = *(const float4*)(s2 + c0 + 4);
    float4 qa = *(const float4*)(q2 + c0),  qb = *(const float4*)(q2 + c0 + 4);
    float4 ga = *(const float4*)(g2 + c0),  gb = *(const float4*)(g2 + c0 + 4);
    float4 ea = *(const float4*)(be2 + c0), eb = *(const float4*)(be2 + c0 + 4);
    float sv[8] = {sa.x,sa.y,sa.z,sa.w,sb.x,sb.y,sb.z,sb.w};
    float qv[8] = {qa.x,qa.y,qa.z,qa.w,qb.x,qb.y,qb.z,qb.w};
    float gv[8] = {ga.x,ga.y,ga.z,ga.w,gb.x,gb.y,gb.z,gb.w};
    float ev[8] = {ea.x,ea.y,ea.z,ea.w,eb.x,eb.y,eb.z,eb.w};
    float scv[8], shv[8];
#pragma unroll
    for (int j = 0; j < 8; ++j) {
        float m = sv[j] * invN;
        float v = qv[j] * invN - m * m;
        float k = gv[j] * rsqrtf(v + 1e-5f);
        scv[j] = k; shv[j] = ev[j] - m * k;
    }
    float mx[8];
#pragma unroll
    for (int j = 0; j < 8; ++j) mx[j] = -3.0e38f;
#pragma unroll
    for (int cell = 0; cell < NB; ++cell) {
        uint4 v = *(const uint4*)(Y2 + ((size_t)(p * NB + cell)) * 1024 + c0);
        const unsigned short* u = (const unsigned short*)&v;
#pragma unroll
        for (int j = 0; j < 8; ++j) {
            float x = fmaf(bf2f(u[j]), scv[j], shv[j]);
            mx[j] = fmaxf(mx[j], x);
        }
    }
    float4 o0, o1;
    o0.x = fmaxf(mx[0], 0.f); o0.y = fmaxf(mx[1], 0.f);
    o0.z = fmaxf(mx[2], 0.f); o0.w = fmaxf(mx[3], 0.f);
    o1.x = fmaxf(mx[4], 0.f); o1.y = fmaxf(mx[5], 0.f);
    o1.z = fmaxf(mx[6], 0.f); o1.w = fmaxf(mx[7], 0.f);
    *(float4*)(out + (size_t)p * 1024 + c0)     = o0;
    *(float4*)(out + (size_t)p * 1024 + c0 + 4) = o1;
}

extern "C" void kernel_launch(void* const* d_in, const int* in_sizes, int n_in,
                              void* d_out, int out_size, void* d_ws, size_t ws_size,
                              hipStream_t stream) {
    const float* h       = (const float*)d_in[0];
    const float* end_pos = (const float*)d_in[1];
    const float* rel_pos = (const float*)d_in[2];
    const float* bpts    = (const float*)d_in[3];
    const float* Wsp     = (const float*)d_in[4];
    const float* bsp     = (const float*)d_in[5];
    const float* W1      = (const float*)d_in[6];
    const float* b1      = (const float*)d_in[7];
    const float* g1      = (const float*)d_in[8];
    const float* be1     = (const float*)d_in[9];
    const float* W2      = (const float*)d_in[10];
    const float* b2      = (const float*)d_in[11];
    const float* g2      = (const float*)d_in[12];
    const float* be2     = (const float*)d_in[13];
    float* out = (float*)d_out;

    char* ws = (char*)d_ws;
    float* s1  = (float*)ws;                 // zeroed by k_prep (first 3072 f32)
    float* q1  = s1 + 512;
    float* s2  = q1 + 512;
    float* q2  = s2 + 1024;
    float* sc1 = q2 + 1024;                  // written by k_finalize
    float* sh1 = sc1 + 512;
    unsigned long long* keys = (unsigned long long*)(ws + 32768);  // [30720] u64
    unsigned short* w1t = (unsigned short*)(ws + 32768 + 245760);  // [512][128]
    unsigned short* w2t = w1t + (size_t)512 * 128;                 // [1024][512]
    unsigned short* X   = w2t + (size_t)1024 * 512;                // [30720][128]
    unsigned short* Y1  = X   + (size_t)MROWS * 128;               // [30720][512]
    unsigned short* Y2  = Y1  + (size_t)MROWS * 512;               // [30720][1024]

    k_prep<<<2048, 256, 0, stream>>>(W1, W2, w1t, w2t, s1, keys);
    k_scan<<<P_N * SPLIT, 256, 0, stream>>>(end_pos, rel_pos, bpts, keys);
    k_assemble<<<P_N, 256, 0, stream>>>(keys, end_pos, rel_pos, bpts, Wsp, bsp, h, X);
    k_gemm<false, true><<<(MROWS / 128) * (512 / 128), 256, 0, stream>>>(
        X, w1t, b1, Y1, MROWS, 512, 128, nullptr, nullptr, s1, q1);
    k_finalize<<<2, 256, 0, stream>>>(s1, q1, g1, be1, sc1, sh1, 512);
    k_gemm<true, true><<<(MROWS / 128) * (1024 / 128), 256, 0, stream>>>(
        Y1, w2t, b2, Y2, MROWS, 1024, 512, sc1, sh1, s2, q2);
    k_bnmax<<<(P_N * 128) / 256, 256, 0, stream>>>(Y2, s2, q2, g2, be2, out);
}